// Round 4
// baseline (3053.586 us; speedup 1.0000x reference)
//
#include <hip/hip_runtime.h>

#define NN 100000
#define NE 800000
#define FIN 16
#define H 64
#define NL 4
#define CDIM 8
#define SCAN_BLOCKS ((NN + 255) / 256)  // 391
#define NT 1563                          // ceil(NN/64)

__device__ __forceinline__ float elu(float x) { return x > 0.f ? x : expm1f(x); }
__device__ __forceinline__ float4 elu4(float4 v) {
    return make_float4(elu(v.x), elu(v.y), elu(v.z), elu(v.w));
}

// ---------------- CSR build ----------------
__global__ __launch_bounds__(256) void k_zero_cnt(int* cnt) {
    int i = blockIdx.x * 256 + threadIdx.x;
    if (i < NN) cnt[i] = 0;
}

__global__ __launch_bounds__(256) void k_count(const int* __restrict__ row, int* cnt) {
    int e = blockIdx.x * 256 + threadIdx.x;
    if (e < NE) atomicAdd(&cnt[row[e]], 1);
}

__global__ __launch_bounds__(256) void k_scan1(const int* __restrict__ cnt,
                                               int* __restrict__ row_ptr,
                                               int* __restrict__ bsum) {
    __shared__ int s[256];
    int t = threadIdx.x, i = blockIdx.x * 256 + t;
    int v = (i < NN) ? cnt[i] : 0;
    s[t] = v;
    __syncthreads();
    for (int off = 1; off < 256; off <<= 1) {
        int x = (t >= off) ? s[t - off] : 0;
        __syncthreads();
        s[t] += x;
        __syncthreads();
    }
    if (i < NN) row_ptr[i] = s[t] - v;
    if (t == 255) bsum[blockIdx.x] = s[255];
}

__global__ __launch_bounds__(512) void k_scan2(const int* __restrict__ bsum,
                                               int* __restrict__ bbase) {
    __shared__ int s[512];
    int t = threadIdx.x;
    int v = (t < SCAN_BLOCKS) ? bsum[t] : 0;
    s[t] = v;
    __syncthreads();
    for (int off = 1; off < 512; off <<= 1) {
        int x = (t >= off) ? s[t - off] : 0;
        __syncthreads();
        s[t] += x;
        __syncthreads();
    }
    if (t < SCAN_BLOCKS) bbase[t] = s[t] - v;
}

__global__ __launch_bounds__(256) void k_scan3(int* __restrict__ row_ptr,
                                               const int* __restrict__ bbase,
                                               int* __restrict__ woff) {
    int t = threadIdx.x, i = blockIdx.x * 256 + t;
    if (i < NN) {
        int v = row_ptr[i] + bbase[blockIdx.x];
        row_ptr[i] = v;
        woff[i] = v;
    }
    if (i == 0) row_ptr[NN] = NE;
}

__global__ __launch_bounds__(256) void k_scatter(const int* __restrict__ row,
                                                 const int* __restrict__ col,
                                                 int* woff, int* __restrict__ cols) {
    int e = blockIdx.x * 256 + threadIdx.x;
    if (e < NE) {
        int r = row[e];
        int p = atomicAdd(&woff[r], 1);
        cols[p] = col[e];
    }
}

// ---------------- encoder L1: h = ELU(x @ w1 + b1), x:(N,16) ----------------
__global__ __launch_bounds__(256) void k_enc1(const float* __restrict__ x,
                                              const float* __restrict__ w1,
                                              const float* __restrict__ b1,
                                              float* __restrict__ h) {
    __shared__ float w1s[FIN * H];
    int tid = threadIdx.x;
    int q = tid >> 6, j = tid & 63;
    for (int t = tid; t < FIN * H; t += 256) w1s[t] = w1[t];
    __syncthreads();
    float bb = b1[j];
    int base = blockIdx.x * 32;
    for (int i = 0; i < 8; i++) {
        int n = base + i * 4 + q;
        float acc = bb;
#pragma unroll
        for (int k = 0; k < FIN; k++) acc += x[n * FIN + k] * w1s[k * H + j];
        h[n * H + j] = elu(acc);
    }
}

// ---------------- encoder L2: feats = ELU(h @ w2 + b2), M4xC4 tile ----------------
__global__ __launch_bounds__(256) void k_enc2(const float* __restrict__ h,
                                              const float* __restrict__ w2,
                                              const float* __restrict__ b2,
                                              float* __restrict__ feats) {
    __shared__ __align__(16) float fs[64 * 68];
    __shared__ __align__(16) float ws[64 * 64];
    int tid = threadIdx.x;
    int base = blockIdx.x * 64;
#pragma unroll
    for (int r = 0; r < 4; r++) {
        int idx = tid + 256 * r;
        ((float4*)ws)[idx] = ((const float4*)w2)[idx];
        int rw = idx >> 4, cc = idx & 15;
        int n = base + rw; if (n >= NN) n = NN - 1;
        *(float4*)&fs[rw * 68 + cc * 4] = *(const float4*)&h[(size_t)n * 64 + cc * 4];
    }
    __syncthreads();
    int cg = tid & 15, ng = tid >> 4;
    int c0 = cg * 4;
    float4 bb = ((const float4*)b2)[cg];
    float4 acc[4];
    acc[0] = bb; acc[1] = bb; acc[2] = bb; acc[3] = bb;
#pragma unroll
    for (int kq = 0; kq < 16; kq++) {
        int k0 = kq * 4;
        float4 w0 = *(const float4*)&ws[(k0 + 0) * 64 + c0];
        float4 w1v = *(const float4*)&ws[(k0 + 1) * 64 + c0];
        float4 w2v = *(const float4*)&ws[(k0 + 2) * 64 + c0];
        float4 w3v = *(const float4*)&ws[(k0 + 3) * 64 + c0];
#pragma unroll
        for (int m = 0; m < 4; m++) {
            float4 f = *(const float4*)&fs[(ng * 4 + m) * 68 + k0];
            acc[m].x += f.x * w0.x + f.y * w1v.x + f.z * w2v.x + f.w * w3v.x;
            acc[m].y += f.x * w0.y + f.y * w1v.y + f.z * w2v.y + f.w * w3v.y;
            acc[m].z += f.x * w0.z + f.y * w1v.z + f.z * w2v.z + f.w * w3v.z;
            acc[m].w += f.x * w0.w + f.y * w1v.w + f.z * w2v.w + f.w * w3v.w;
        }
    }
#pragma unroll
    for (int m = 0; m < 4; m++) {
        int n = base + ng * 4 + m;
        if (n < NN) *(float4*)&feats[(size_t)n * 64 + c0] = elu4(acc[m]);
    }
}

// ---------------- A = f@(Wt-Wb)+cb ; B = f@Wb ; M4xC4, dual-W ----------------
__global__ __launch_bounds__(256) void k_ab(const float* __restrict__ feats,
                                            const float* __restrict__ convw,
                                            const float* __restrict__ convb,
                                            float* __restrict__ A, float* __restrict__ Bm) {
    __shared__ __align__(16) float fs[64 * 68];
    __shared__ __align__(16) float was[64 * 64];
    __shared__ __align__(16) float wbs[64 * 64];
    int tid = threadIdx.x;
    int base = blockIdx.x * 64;
#pragma unroll
    for (int r = 0; r < 4; r++) {
        int idx = tid + 256 * r;
        float4 wt = ((const float4*)convw)[idx];
        float4 wb = ((const float4*)convw)[1024 + idx];
        ((float4*)was)[idx] = make_float4(wt.x - wb.x, wt.y - wb.y, wt.z - wb.z, wt.w - wb.w);
        ((float4*)wbs)[idx] = wb;
        int rw = idx >> 4, cc = idx & 15;
        int n = base + rw; if (n >= NN) n = NN - 1;
        *(float4*)&fs[rw * 68 + cc * 4] = *(const float4*)&feats[(size_t)n * 64 + cc * 4];
    }
    __syncthreads();
    int cg = tid & 15, ng = tid >> 4;
    int c0 = cg * 4;
    float4 cb = ((const float4*)convb)[cg];
    float4 accA[4], accB[4];
    float4 z = make_float4(0.f, 0.f, 0.f, 0.f);
    accA[0] = cb; accA[1] = cb; accA[2] = cb; accA[3] = cb;
    accB[0] = z; accB[1] = z; accB[2] = z; accB[3] = z;
#pragma unroll
    for (int kq = 0; kq < 16; kq++) {
        int k0 = kq * 4;
        float4 a0 = *(const float4*)&was[(k0 + 0) * 64 + c0];
        float4 a1 = *(const float4*)&was[(k0 + 1) * 64 + c0];
        float4 a2 = *(const float4*)&was[(k0 + 2) * 64 + c0];
        float4 a3 = *(const float4*)&was[(k0 + 3) * 64 + c0];
        float4 b0 = *(const float4*)&wbs[(k0 + 0) * 64 + c0];
        float4 b1v = *(const float4*)&wbs[(k0 + 1) * 64 + c0];
        float4 b2v = *(const float4*)&wbs[(k0 + 2) * 64 + c0];
        float4 b3v = *(const float4*)&wbs[(k0 + 3) * 64 + c0];
#pragma unroll
        for (int m = 0; m < 4; m++) {
            float4 f = *(const float4*)&fs[(ng * 4 + m) * 68 + k0];
            accA[m].x += f.x * a0.x + f.y * a1.x + f.z * a2.x + f.w * a3.x;
            accA[m].y += f.x * a0.y + f.y * a1.y + f.z * a2.y + f.w * a3.y;
            accA[m].z += f.x * a0.z + f.y * a1.z + f.z * a2.z + f.w * a3.z;
            accA[m].w += f.x * a0.w + f.y * a1.w + f.z * a2.w + f.w * a3.w;
            accB[m].x += f.x * b0.x + f.y * b1v.x + f.z * b2v.x + f.w * b3v.x;
            accB[m].y += f.x * b0.y + f.y * b1v.y + f.z * b2v.y + f.w * b3v.y;
            accB[m].z += f.x * b0.z + f.y * b1v.z + f.z * b2v.z + f.w * b3v.z;
            accB[m].w += f.x * b0.w + f.y * b1v.w + f.z * b2v.w + f.w * b3v.w;
        }
    }
#pragma unroll
    for (int m = 0; m < 4; m++) {
        int n = base + ng * 4 + m;
        if (n < NN) {
            *(float4*)&A[(size_t)n * 64 + c0] = accA[m];
            *(float4*)&Bm[(size_t)n * 64 + c0] = accB[m];
        }
    }
}

// ---------------- CSR gather: 4 edges per instr, no atomics ----------------
__global__ __launch_bounds__(256) void k_gather(const float* __restrict__ A,
                                                const float* __restrict__ Bm,
                                                const int* __restrict__ row_ptr,
                                                const int* __restrict__ cols,
                                                const float* __restrict__ gamma,
                                                const float* __restrict__ beta,
                                                float* __restrict__ feats) {
    int tid = threadIdx.x;
    int wave = tid >> 6, lane = tid & 63;
    int n = blockIdx.x * 4 + wave;
    int g = lane >> 4, c4 = lane & 15, c0 = c4 * 4;
    int s = row_ptr[n], e = row_ptr[n + 1];
    int cnt = e - s;
    float4 a = *(const float4*)&A[(size_t)n * H + c0];
    float4 acc = make_float4(0.f, 0.f, 0.f, 0.f);
    for (int p0 = s; p0 < e; p0 += 4) {
        int p = p0 + g;
        bool valid = p < e;
        int c = cols[valid ? p : (e - 1)];
        float4 b = *(const float4*)&Bm[(size_t)c * H + c0];
        float4 v = elu4(make_float4(a.x + b.x, a.y + b.y, a.z + b.z, a.w + b.w));
        if (valid) {
            acc.x += v.x; acc.y += v.y; acc.z += v.z; acc.w += v.w;
        }
    }
    acc.x += __shfl_xor(acc.x, 16); acc.y += __shfl_xor(acc.y, 16);
    acc.z += __shfl_xor(acc.z, 16); acc.w += __shfl_xor(acc.w, 16);
    acc.x += __shfl_xor(acc.x, 32); acc.y += __shfl_xor(acc.y, 32);
    acc.z += __shfl_xor(acc.z, 32); acc.w += __shfl_xor(acc.w, 32);
    if (g == 0 && cnt > 0) {
        const float bs = 0.99999500003749968750f;  // 1/sqrt(1+1e-5)
        float inv = bs / (float)cnt;
        float4 gm = *(const float4*)&gamma[c0];
        float4 bt = *(const float4*)&beta[c0];
        float4 f = *(float4*)&feats[(size_t)n * H + c0];
        f.x += acc.x * gm.x * inv + bt.x;
        f.y += acc.y * gm.y * inv + bt.y;
        f.z += acc.z * gm.z * inv + bt.z;
        f.w += acc.w * gm.w * inv + bt.w;
        *(float4*)&feats[(size_t)n * H + c0] = f;
    }
}

// ---------------- fused 3-layer head ----------------
__global__ __launch_bounds__(256) void k_head(const float* __restrict__ feats,
                                              const float* __restrict__ w1,
                                              const float* __restrict__ b1,
                                              const float* __restrict__ w2,
                                              const float* __restrict__ b2,
                                              const float* __restrict__ w3,
                                              const float* __restrict__ b3,
                                              float* __restrict__ out) {
    __shared__ __align__(16) float fs[64 * 68];   // also reused as o2s
    __shared__ __align__(16) float w1s[64 * 64];
    __shared__ __align__(16) float o1s[64 * 68];
    __shared__ __align__(16) float w2s[64 * 32];
    __shared__ __align__(16) float w3s[32 * 8];
    int tid = threadIdx.x;
    int base = blockIdx.x * 64;
#pragma unroll
    for (int r = 0; r < 4; r++) {
        int idx = tid + 256 * r;
        ((float4*)w1s)[idx] = ((const float4*)w1)[idx];
        int rw = idx >> 4, cc = idx & 15;
        int n = base + rw; if (n >= NN) n = NN - 1;
        *(float4*)&fs[rw * 68 + cc * 4] = *(const float4*)&feats[(size_t)n * 64 + cc * 4];
    }
    ((float4*)w2s)[tid] = ((const float4*)w2)[tid];
    ((float4*)w2s)[tid + 256] = ((const float4*)w2)[tid + 256];
    if (tid < 64) ((float4*)w3s)[tid] = ((const float4*)w3)[tid];
    __syncthreads();

    // layer 1: 64->64, M4xC4
    int cg = tid & 15, ng = tid >> 4;
    int c0 = cg * 4;
    {
        float4 bb = ((const float4*)b1)[cg];
        float4 acc[4];
        acc[0] = bb; acc[1] = bb; acc[2] = bb; acc[3] = bb;
#pragma unroll
        for (int kq = 0; kq < 16; kq++) {
            int k0 = kq * 4;
            float4 w0 = *(const float4*)&w1s[(k0 + 0) * 64 + c0];
            float4 w1v = *(const float4*)&w1s[(k0 + 1) * 64 + c0];
            float4 w2v = *(const float4*)&w1s[(k0 + 2) * 64 + c0];
            float4 w3v = *(const float4*)&w1s[(k0 + 3) * 64 + c0];
#pragma unroll
            for (int m = 0; m < 4; m++) {
                float4 f = *(const float4*)&fs[(ng * 4 + m) * 68 + k0];
                acc[m].x += f.x * w0.x + f.y * w1v.x + f.z * w2v.x + f.w * w3v.x;
                acc[m].y += f.x * w0.y + f.y * w1v.y + f.z * w2v.y + f.w * w3v.y;
                acc[m].z += f.x * w0.z + f.y * w1v.z + f.z * w2v.z + f.w * w3v.z;
                acc[m].w += f.x * w0.w + f.y * w1v.w + f.z * w2v.w + f.w * w3v.w;
            }
        }
        __syncthreads();  // all fs reads done (fs reused below)
#pragma unroll
        for (int m = 0; m < 4; m++)
            *(float4*)&o1s[(ng * 4 + m) * 68 + c0] = elu4(acc[m]);
    }
    __syncthreads();

    // layer 2: 64->32, M2xC4
    float* o2s = fs;  // alias; fs is dead
    {
        int cg2 = tid & 7, ng2 = tid >> 3;
        int c20 = cg2 * 4;
        float4 bb = ((const float4*)b2)[cg2];
        float4 acc[2];
        acc[0] = bb; acc[1] = bb;
#pragma unroll
        for (int kq = 0; kq < 16; kq++) {
            int k0 = kq * 4;
            float4 w0 = *(const float4*)&w2s[(k0 + 0) * 32 + c20];
            float4 w1v = *(const float4*)&w2s[(k0 + 1) * 32 + c20];
            float4 w2v = *(const float4*)&w2s[(k0 + 2) * 32 + c20];
            float4 w3v = *(const float4*)&w2s[(k0 + 3) * 32 + c20];
#pragma unroll
            for (int m = 0; m < 2; m++) {
                float4 f = *(const float4*)&o1s[(ng2 * 2 + m) * 68 + k0];
                acc[m].x += f.x * w0.x + f.y * w1v.x + f.z * w2v.x + f.w * w3v.x;
                acc[m].y += f.x * w0.y + f.y * w1v.y + f.z * w2v.y + f.w * w3v.y;
                acc[m].z += f.x * w0.z + f.y * w1v.z + f.z * w2v.z + f.w * w3v.z;
                acc[m].w += f.x * w0.w + f.y * w1v.w + f.z * w2v.w + f.w * w3v.w;
            }
        }
#pragma unroll
        for (int m = 0; m < 2; m++)
            *(float4*)&o2s[(ng2 * 2 + m) * 40 + c20] = elu4(acc[m]);
    }
    __syncthreads();

    // layer 3: 32->8, first 128 threads, M1xC4
    if (tid < 128) {
        int n3 = tid >> 1, c30 = (tid & 1) * 4;
        float4 acc = ((const float4*)b3)[tid & 1];
#pragma unroll
        for (int kq = 0; kq < 8; kq++) {
            int k0 = kq * 4;
            float4 w0 = *(const float4*)&w3s[(k0 + 0) * 8 + c30];
            float4 w1v = *(const float4*)&w3s[(k0 + 1) * 8 + c30];
            float4 w2v = *(const float4*)&w3s[(k0 + 2) * 8 + c30];
            float4 w3v = *(const float4*)&w3s[(k0 + 3) * 8 + c30];
            float4 f = *(const float4*)&o2s[n3 * 40 + k0];
            acc.x += f.x * w0.x + f.y * w1v.x + f.z * w2v.x + f.w * w3v.x;
            acc.y += f.x * w0.y + f.y * w1v.y + f.z * w2v.y + f.w * w3v.y;
            acc.z += f.x * w0.z + f.y * w1v.z + f.z * w2v.z + f.w * w3v.z;
            acc.w += f.x * w0.w + f.y * w1v.w + f.z * w2v.w + f.w * w3v.w;
        }
        int n = base + n3;
        if (n < NN) *(float4*)&out[(size_t)n * 8 + c30] = acc;
    }
}

__global__ __launch_bounds__(256) void k_batch(const int* __restrict__ batch,
                                               float* __restrict__ out) {
    int i = blockIdx.x * 256 + threadIdx.x;
    if (i < NN) out[i] = (float)batch[i];
}

extern "C" void kernel_launch(void* const* d_in, const int* in_sizes, int n_in,
                              void* d_out, int out_size, void* d_ws, size_t ws_size,
                              hipStream_t stream) {
    const float* x = (const float*)d_in[0];
    const int* edge_index = (const int*)d_in[1];
    const int* batch = (const int*)d_in[2];
    const float* enc_w1 = (const float*)d_in[3];
    const float* enc_b1 = (const float*)d_in[4];
    const float* enc_w2 = (const float*)d_in[5];
    const float* enc_b2 = (const float*)d_in[6];
    const float* conv_w = (const float*)d_in[7];
    const float* conv_b = (const float*)d_in[8];
    const float* bn_gamma = (const float*)d_in[9];
    const float* bn_beta = (const float*)d_in[10];
    const float* out_w1 = (const float*)d_in[11];
    const float* out_b1 = (const float*)d_in[12];
    const float* out_w2 = (const float*)d_in[13];
    const float* out_b2 = (const float*)d_in[14];
    const float* out_w3 = (const float*)d_in[15];
    const float* out_b3 = (const float*)d_in[16];

    const int* row = edge_index;
    const int* col = edge_index + NE;

    float* feats = (float*)d_ws;               // N*H
    float* Abuf = feats + (size_t)NN * H;      // N*H
    float* Bbuf = Abuf + (size_t)NN * H;       // N*H
    int* cnt = (int*)(Bbuf + (size_t)NN * H);  // N
    int* row_ptr = cnt + NN;                   // N+1
    int* woff = row_ptr + NN + 1;              // N
    int* cols = woff + NN;                     // E
    int* bsum = cols + NE;                     // 512
    int* bbase = bsum + 512;                   // 512
    float* h = Abuf;                           // encoder hidden reuses A

    float* out = (float*)d_out;

    k_zero_cnt<<<(NN + 255) / 256, 256, 0, stream>>>(cnt);
    k_count<<<(NE + 255) / 256, 256, 0, stream>>>(row, cnt);
    k_scan1<<<SCAN_BLOCKS, 256, 0, stream>>>(cnt, row_ptr, bsum);
    k_scan2<<<1, 512, 0, stream>>>(bsum, bbase);
    k_scan3<<<SCAN_BLOCKS, 256, 0, stream>>>(row_ptr, bbase, woff);
    k_scatter<<<(NE + 255) / 256, 256, 0, stream>>>(row, col, woff, cols);

    k_enc1<<<NN / 32, 256, 0, stream>>>(x, enc_w1, enc_b1, h);
    k_enc2<<<NT, 256, 0, stream>>>(h, enc_w2, enc_b2, feats);

    for (int i = 0; i < NL; i++) {
        k_ab<<<NT, 256, 0, stream>>>(feats, conv_w + (size_t)i * 2 * H * H,
                                     conv_b + (size_t)i * H, Abuf, Bbuf);
        k_gather<<<NN / 4, 256, 0, stream>>>(Abuf, Bbuf, row_ptr, cols,
                                             bn_gamma + (size_t)i * H,
                                             bn_beta + (size_t)i * H, feats);
    }

    k_head<<<NT, 256, 0, stream>>>(feats, out_w1, out_b1, out_w2, out_b2,
                                   out_w3, out_b3, out);
    k_batch<<<(NN + 255) / 256, 256, 0, stream>>>(batch, out + (size_t)NN * CDIM);
}

// Round 5
// 616.123 us; speedup vs baseline: 4.9561x; 4.9561x over previous
//
#include <hip/hip_runtime.h>

#define NN 100000
#define NE 800000
#define FIN 16
#define H 64
#define NL 4
#define CDIM 8
#define SCAN_BLOCKS ((NN + 255) / 256)  // 391
#define NT 1563                          // ceil(NN/64)

__device__ __forceinline__ float elu(float x) { return x > 0.f ? x : expm1f(x); }
__device__ __forceinline__ float4 elu4(float4 v) {
    return make_float4(elu(v.x), elu(v.y), elu(v.z), elu(v.w));
}

// ---------------- CSR build ----------------
__global__ __launch_bounds__(256) void k_zero_cnt(int* cnt) {
    int i = blockIdx.x * 256 + threadIdx.x;
    if (i < NN) cnt[i] = 0;
}

__global__ __launch_bounds__(256) void k_count(const int* __restrict__ row, int* cnt) {
    int e = blockIdx.x * 256 + threadIdx.x;
    if (e < NE) atomicAdd(&cnt[row[e]], 1);
}

__global__ __launch_bounds__(256) void k_scan1(const int* __restrict__ cnt,
                                               int* __restrict__ row_ptr,
                                               int* __restrict__ bsum) {
    __shared__ int s[256];
    int t = threadIdx.x, i = blockIdx.x * 256 + t;
    int v = (i < NN) ? cnt[i] : 0;
    s[t] = v;
    __syncthreads();
    for (int off = 1; off < 256; off <<= 1) {
        int x = (t >= off) ? s[t - off] : 0;
        __syncthreads();
        s[t] += x;
        __syncthreads();
    }
    if (i < NN) row_ptr[i] = s[t] - v;
    if (t == 255) bsum[blockIdx.x] = s[255];
}

__global__ __launch_bounds__(512) void k_scan2(const int* __restrict__ bsum,
                                               int* __restrict__ bbase) {
    __shared__ int s[512];
    int t = threadIdx.x;
    int v = (t < SCAN_BLOCKS) ? bsum[t] : 0;
    s[t] = v;
    __syncthreads();
    for (int off = 1; off < 512; off <<= 1) {
        int x = (t >= off) ? s[t - off] : 0;
        __syncthreads();
        s[t] += x;
        __syncthreads();
    }
    if (t < SCAN_BLOCKS) bbase[t] = s[t] - v;
}

__global__ __launch_bounds__(256) void k_scan3(int* __restrict__ row_ptr,
                                               const int* __restrict__ bbase,
                                               int* __restrict__ woff) {
    int t = threadIdx.x, i = blockIdx.x * 256 + t;
    if (i < NN) {
        int v = row_ptr[i] + bbase[blockIdx.x];
        row_ptr[i] = v;
        woff[i] = v;
    }
    if (i == 0) row_ptr[NN] = NE;
}

__global__ __launch_bounds__(256) void k_scatter(const int* __restrict__ row,
                                                 const int* __restrict__ col,
                                                 int* woff, int* __restrict__ cols) {
    int e = blockIdx.x * 256 + threadIdx.x;
    if (e < NE) {
        int r = row[e];
        int p = atomicAdd(&woff[r], 1);
        cols[p] = col[e];
    }
}

// ---------------- encoder L1: h = ELU(x @ w1 + b1), x:(N,16) ----------------
__global__ __launch_bounds__(256) void k_enc1(const float* __restrict__ x,
                                              const float* __restrict__ w1,
                                              const float* __restrict__ b1,
                                              float* __restrict__ h) {
    __shared__ float w1s[FIN * H];
    int tid = threadIdx.x;
    int q = tid >> 6, j = tid & 63;
    for (int t = tid; t < FIN * H; t += 256) w1s[t] = w1[t];
    __syncthreads();
    float bb = b1[j];
    int base = blockIdx.x * 32;
    for (int i = 0; i < 8; i++) {
        int n = base + i * 4 + q;
        float acc = bb;
#pragma unroll
        for (int k = 0; k < FIN; k++) acc += x[n * FIN + k] * w1s[k * H + j];
        h[n * H + j] = elu(acc);
    }
}

// ---------------- encoder L2: feats = ELU(h @ w2 + b2), M4xC4 tile ----------------
__global__ __launch_bounds__(256) void k_enc2(const float* __restrict__ h,
                                              const float* __restrict__ w2,
                                              const float* __restrict__ b2,
                                              float* __restrict__ feats) {
    __shared__ __align__(16) float fs[64 * 68];
    __shared__ __align__(16) float ws[64 * 64];
    int tid = threadIdx.x;
    int base = blockIdx.x * 64;
#pragma unroll
    for (int r = 0; r < 4; r++) {
        int idx = tid + 256 * r;
        ((float4*)ws)[idx] = ((const float4*)w2)[idx];
        int rw = idx >> 4, cc = idx & 15;
        int n = base + rw; if (n >= NN) n = NN - 1;
        *(float4*)&fs[rw * 68 + cc * 4] = *(const float4*)&h[(size_t)n * 64 + cc * 4];
    }
    __syncthreads();
    int cg = tid & 15, ng = tid >> 4;
    int c0 = cg * 4;
    float4 bb = ((const float4*)b2)[cg];
    float4 acc[4];
    acc[0] = bb; acc[1] = bb; acc[2] = bb; acc[3] = bb;
#pragma unroll 2
    for (int kq = 0; kq < 16; kq++) {
        int k0 = kq * 4;
        float4 w0 = *(const float4*)&ws[(k0 + 0) * 64 + c0];
        float4 w1v = *(const float4*)&ws[(k0 + 1) * 64 + c0];
        float4 w2v = *(const float4*)&ws[(k0 + 2) * 64 + c0];
        float4 w3v = *(const float4*)&ws[(k0 + 3) * 64 + c0];
#pragma unroll
        for (int m = 0; m < 4; m++) {
            float4 f = *(const float4*)&fs[(ng * 4 + m) * 68 + k0];
            acc[m].x += f.x * w0.x + f.y * w1v.x + f.z * w2v.x + f.w * w3v.x;
            acc[m].y += f.x * w0.y + f.y * w1v.y + f.z * w2v.y + f.w * w3v.y;
            acc[m].z += f.x * w0.z + f.y * w1v.z + f.z * w2v.z + f.w * w3v.z;
            acc[m].w += f.x * w0.w + f.y * w1v.w + f.z * w2v.w + f.w * w3v.w;
        }
    }
#pragma unroll
    for (int m = 0; m < 4; m++) {
        int n = base + ng * 4 + m;
        if (n < NN) *(float4*)&feats[(size_t)n * 64 + c0] = elu4(acc[m]);
    }
}

// ---- A = f@(Wt-Wb)+cb ; B = f@Wb ; M4xC4, TWO k-passes (register pressure) ----
__global__ __launch_bounds__(256) void k_ab(const float* __restrict__ feats,
                                            const float* __restrict__ convw,
                                            const float* __restrict__ convb,
                                            float* __restrict__ A, float* __restrict__ Bm) {
    __shared__ __align__(16) float fs[64 * 68];
    __shared__ __align__(16) float was[64 * 64];
    __shared__ __align__(16) float wbs[64 * 64];
    int tid = threadIdx.x;
    int base = blockIdx.x * 64;
#pragma unroll
    for (int r = 0; r < 4; r++) {
        int idx = tid + 256 * r;
        float4 wt = ((const float4*)convw)[idx];
        float4 wb = ((const float4*)convw)[1024 + idx];
        ((float4*)was)[idx] = make_float4(wt.x - wb.x, wt.y - wb.y, wt.z - wb.z, wt.w - wb.w);
        ((float4*)wbs)[idx] = wb;
        int rw = idx >> 4, cc = idx & 15;
        int n = base + rw; if (n >= NN) n = NN - 1;
        *(float4*)&fs[rw * 68 + cc * 4] = *(const float4*)&feats[(size_t)n * 64 + cc * 4];
    }
    __syncthreads();
    int cg = tid & 15, ng = tid >> 4;
    int c0 = cg * 4;

    // pass 1: A = f @ (Wt-Wb) + cb
    {
        float4 cb = ((const float4*)convb)[cg];
        float4 acc[4];
        acc[0] = cb; acc[1] = cb; acc[2] = cb; acc[3] = cb;
#pragma unroll 2
        for (int kq = 0; kq < 16; kq++) {
            int k0 = kq * 4;
            float4 w0 = *(const float4*)&was[(k0 + 0) * 64 + c0];
            float4 w1v = *(const float4*)&was[(k0 + 1) * 64 + c0];
            float4 w2v = *(const float4*)&was[(k0 + 2) * 64 + c0];
            float4 w3v = *(const float4*)&was[(k0 + 3) * 64 + c0];
#pragma unroll
            for (int m = 0; m < 4; m++) {
                float4 f = *(const float4*)&fs[(ng * 4 + m) * 68 + k0];
                acc[m].x += f.x * w0.x + f.y * w1v.x + f.z * w2v.x + f.w * w3v.x;
                acc[m].y += f.x * w0.y + f.y * w1v.y + f.z * w2v.y + f.w * w3v.y;
                acc[m].z += f.x * w0.z + f.y * w1v.z + f.z * w2v.z + f.w * w3v.z;
                acc[m].w += f.x * w0.w + f.y * w1v.w + f.z * w2v.w + f.w * w3v.w;
            }
        }
#pragma unroll
        for (int m = 0; m < 4; m++) {
            int n = base + ng * 4 + m;
            if (n < NN) *(float4*)&A[(size_t)n * 64 + c0] = acc[m];
        }
    }

    // pass 2: B = f @ Wb
    {
        float4 z = make_float4(0.f, 0.f, 0.f, 0.f);
        float4 acc[4];
        acc[0] = z; acc[1] = z; acc[2] = z; acc[3] = z;
#pragma unroll 2
        for (int kq = 0; kq < 16; kq++) {
            int k0 = kq * 4;
            float4 w0 = *(const float4*)&wbs[(k0 + 0) * 64 + c0];
            float4 w1v = *(const float4*)&wbs[(k0 + 1) * 64 + c0];
            float4 w2v = *(const float4*)&wbs[(k0 + 2) * 64 + c0];
            float4 w3v = *(const float4*)&wbs[(k0 + 3) * 64 + c0];
#pragma unroll
            for (int m = 0; m < 4; m++) {
                float4 f = *(const float4*)&fs[(ng * 4 + m) * 68 + k0];
                acc[m].x += f.x * w0.x + f.y * w1v.x + f.z * w2v.x + f.w * w3v.x;
                acc[m].y += f.x * w0.y + f.y * w1v.y + f.z * w2v.y + f.w * w3v.y;
                acc[m].z += f.x * w0.z + f.y * w1v.z + f.z * w2v.z + f.w * w3v.z;
                acc[m].w += f.x * w0.w + f.y * w1v.w + f.z * w2v.w + f.w * w3v.w;
            }
        }
#pragma unroll
        for (int m = 0; m < 4; m++) {
            int n = base + ng * 4 + m;
            if (n < NN) *(float4*)&Bm[(size_t)n * 64 + c0] = acc[m];
        }
    }
}

// ---------------- CSR gather: 4 edges per instr, no atomics ----------------
__global__ __launch_bounds__(256) void k_gather(const float* __restrict__ A,
                                                const float* __restrict__ Bm,
                                                const int* __restrict__ row_ptr,
                                                const int* __restrict__ cols,
                                                const float* __restrict__ gamma,
                                                const float* __restrict__ beta,
                                                float* __restrict__ feats) {
    int tid = threadIdx.x;
    int wave = tid >> 6, lane = tid & 63;
    int n = blockIdx.x * 4 + wave;
    int g = lane >> 4, c4 = lane & 15, c0 = c4 * 4;
    int s = row_ptr[n], e = row_ptr[n + 1];
    int cnt = e - s;
    float4 a = *(const float4*)&A[(size_t)n * H + c0];
    float4 acc = make_float4(0.f, 0.f, 0.f, 0.f);
    for (int p0 = s; p0 < e; p0 += 4) {
        int p = p0 + g;
        bool valid = p < e;
        int c = cols[valid ? p : (e - 1)];
        float4 b = *(const float4*)&Bm[(size_t)c * H + c0];
        float4 v = elu4(make_float4(a.x + b.x, a.y + b.y, a.z + b.z, a.w + b.w));
        if (valid) {
            acc.x += v.x; acc.y += v.y; acc.z += v.z; acc.w += v.w;
        }
    }
    acc.x += __shfl_xor(acc.x, 16); acc.y += __shfl_xor(acc.y, 16);
    acc.z += __shfl_xor(acc.z, 16); acc.w += __shfl_xor(acc.w, 16);
    acc.x += __shfl_xor(acc.x, 32); acc.y += __shfl_xor(acc.y, 32);
    acc.z += __shfl_xor(acc.z, 32); acc.w += __shfl_xor(acc.w, 32);
    if (g == 0 && cnt > 0) {
        const float bs = 0.99999500003749968750f;  // 1/sqrt(1+1e-5)
        float inv = bs / (float)cnt;
        float4 gm = *(const float4*)&gamma[c0];
        float4 bt = *(const float4*)&beta[c0];
        float4 f = *(float4*)&feats[(size_t)n * H + c0];
        f.x += acc.x * gm.x * inv + bt.x;
        f.y += acc.y * gm.y * inv + bt.y;
        f.z += acc.z * gm.z * inv + bt.z;
        f.w += acc.w * gm.w * inv + bt.w;
        *(float4*)&feats[(size_t)n * H + c0] = f;
    }
}

// ---------------- fused 3-layer head ----------------
__global__ __launch_bounds__(256) void k_head(const float* __restrict__ feats,
                                              const float* __restrict__ w1,
                                              const float* __restrict__ b1,
                                              const float* __restrict__ w2,
                                              const float* __restrict__ b2,
                                              const float* __restrict__ w3,
                                              const float* __restrict__ b3,
                                              float* __restrict__ out) {
    __shared__ __align__(16) float fs[64 * 68];   // also reused as o2s
    __shared__ __align__(16) float w1s[64 * 64];
    __shared__ __align__(16) float o1s[64 * 68];
    __shared__ __align__(16) float w2s[64 * 32];
    __shared__ __align__(16) float w3s[32 * 8];
    int tid = threadIdx.x;
    int base = blockIdx.x * 64;
#pragma unroll
    for (int r = 0; r < 4; r++) {
        int idx = tid + 256 * r;
        ((float4*)w1s)[idx] = ((const float4*)w1)[idx];
        int rw = idx >> 4, cc = idx & 15;
        int n = base + rw; if (n >= NN) n = NN - 1;
        *(float4*)&fs[rw * 68 + cc * 4] = *(const float4*)&feats[(size_t)n * 64 + cc * 4];
    }
    ((float4*)w2s)[tid] = ((const float4*)w2)[tid];
    ((float4*)w2s)[tid + 256] = ((const float4*)w2)[tid + 256];
    if (tid < 64) ((float4*)w3s)[tid] = ((const float4*)w3)[tid];
    __syncthreads();

    // layer 1: 64->64, M4xC4
    int cg = tid & 15, ng = tid >> 4;
    int c0 = cg * 4;
    {
        float4 bb = ((const float4*)b1)[cg];
        float4 acc[4];
        acc[0] = bb; acc[1] = bb; acc[2] = bb; acc[3] = bb;
#pragma unroll 2
        for (int kq = 0; kq < 16; kq++) {
            int k0 = kq * 4;
            float4 w0 = *(const float4*)&w1s[(k0 + 0) * 64 + c0];
            float4 w1v = *(const float4*)&w1s[(k0 + 1) * 64 + c0];
            float4 w2v = *(const float4*)&w1s[(k0 + 2) * 64 + c0];
            float4 w3v = *(const float4*)&w1s[(k0 + 3) * 64 + c0];
#pragma unroll
            for (int m = 0; m < 4; m++) {
                float4 f = *(const float4*)&fs[(ng * 4 + m) * 68 + k0];
                acc[m].x += f.x * w0.x + f.y * w1v.x + f.z * w2v.x + f.w * w3v.x;
                acc[m].y += f.x * w0.y + f.y * w1v.y + f.z * w2v.y + f.w * w3v.y;
                acc[m].z += f.x * w0.z + f.y * w1v.z + f.z * w2v.z + f.w * w3v.z;
                acc[m].w += f.x * w0.w + f.y * w1v.w + f.z * w2v.w + f.w * w3v.w;
            }
        }
        __syncthreads();  // all fs reads done (fs reused below)
#pragma unroll
        for (int m = 0; m < 4; m++)
            *(float4*)&o1s[(ng * 4 + m) * 68 + c0] = elu4(acc[m]);
    }
    __syncthreads();

    // layer 2: 64->32, M2xC4
    float* o2s = fs;  // alias; fs is dead
    {
        int cg2 = tid & 7, ng2 = tid >> 3;
        int c20 = cg2 * 4;
        float4 bb = ((const float4*)b2)[cg2];
        float4 acc[2];
        acc[0] = bb; acc[1] = bb;
#pragma unroll 2
        for (int kq = 0; kq < 16; kq++) {
            int k0 = kq * 4;
            float4 w0 = *(const float4*)&w2s[(k0 + 0) * 32 + c20];
            float4 w1v = *(const float4*)&w2s[(k0 + 1) * 32 + c20];
            float4 w2v = *(const float4*)&w2s[(k0 + 2) * 32 + c20];
            float4 w3v = *(const float4*)&w2s[(k0 + 3) * 32 + c20];
#pragma unroll
            for (int m = 0; m < 2; m++) {
                float4 f = *(const float4*)&o1s[(ng2 * 2 + m) * 68 + k0];
                acc[m].x += f.x * w0.x + f.y * w1v.x + f.z * w2v.x + f.w * w3v.x;
                acc[m].y += f.x * w0.y + f.y * w1v.y + f.z * w2v.y + f.w * w3v.y;
                acc[m].z += f.x * w0.z + f.y * w1v.z + f.z * w2v.z + f.w * w3v.z;
                acc[m].w += f.x * w0.w + f.y * w1v.w + f.z * w2v.w + f.w * w3v.w;
            }
        }
#pragma unroll
        for (int m = 0; m < 2; m++)
            *(float4*)&o2s[(ng2 * 2 + m) * 40 + c20] = elu4(acc[m]);
    }
    __syncthreads();

    // layer 3: 32->8, first 128 threads, M1xC4
    if (tid < 128) {
        int n3 = tid >> 1, c30 = (tid & 1) * 4;
        float4 acc = ((const float4*)b3)[tid & 1];
#pragma unroll 2
        for (int kq = 0; kq < 8; kq++) {
            int k0 = kq * 4;
            float4 w0 = *(const float4*)&w3s[(k0 + 0) * 8 + c30];
            float4 w1v = *(const float4*)&w3s[(k0 + 1) * 8 + c30];
            float4 w2v = *(const float4*)&w3s[(k0 + 2) * 8 + c30];
            float4 w3v = *(const float4*)&w3s[(k0 + 3) * 8 + c30];
            float4 f = *(const float4*)&o2s[n3 * 40 + k0];
            acc.x += f.x * w0.x + f.y * w1v.x + f.z * w2v.x + f.w * w3v.x;
            acc.y += f.x * w0.y + f.y * w1v.y + f.z * w2v.y + f.w * w3v.y;
            acc.z += f.x * w0.z + f.y * w1v.z + f.z * w2v.z + f.w * w3v.z;
            acc.w += f.x * w0.w + f.y * w1v.w + f.z * w2v.w + f.w * w3v.w;
        }
        int n = base + n3;
        if (n < NN) *(float4*)&out[(size_t)n * 8 + c30] = acc;
    }
}

__global__ __launch_bounds__(256) void k_batch(const int* __restrict__ batch,
                                               float* __restrict__ out) {
    int i = blockIdx.x * 256 + threadIdx.x;
    if (i < NN) out[i] = (float)batch[i];
}

extern "C" void kernel_launch(void* const* d_in, const int* in_sizes, int n_in,
                              void* d_out, int out_size, void* d_ws, size_t ws_size,
                              hipStream_t stream) {
    const float* x = (const float*)d_in[0];
    const int* edge_index = (const int*)d_in[1];
    const int* batch = (const int*)d_in[2];
    const float* enc_w1 = (const float*)d_in[3];
    const float* enc_b1 = (const float*)d_in[4];
    const float* enc_w2 = (const float*)d_in[5];
    const float* enc_b2 = (const float*)d_in[6];
    const float* conv_w = (const float*)d_in[7];
    const float* conv_b = (const float*)d_in[8];
    const float* bn_gamma = (const float*)d_in[9];
    const float* bn_beta = (const float*)d_in[10];
    const float* out_w1 = (const float*)d_in[11];
    const float* out_b1 = (const float*)d_in[12];
    const float* out_w2 = (const float*)d_in[13];
    const float* out_b2 = (const float*)d_in[14];
    const float* out_w3 = (const float*)d_in[15];
    const float* out_b3 = (const float*)d_in[16];

    const int* row = edge_index;
    const int* col = edge_index + NE;

    float* feats = (float*)d_ws;               // N*H
    float* Abuf = feats + (size_t)NN * H;      // N*H
    float* Bbuf = Abuf + (size_t)NN * H;       // N*H
    int* cnt = (int*)(Bbuf + (size_t)NN * H);  // N
    int* row_ptr = cnt + NN;                   // N+1
    int* woff = row_ptr + NN + 1;              // N
    int* cols = woff + NN;                     // E
    int* bsum = cols + NE;                     // 512
    int* bbase = bsum + 512;                   // 512
    float* h = Abuf;                           // encoder hidden reuses A

    float* out = (float*)d_out;

    k_zero_cnt<<<(NN + 255) / 256, 256, 0, stream>>>(cnt);
    k_count<<<(NE + 255) / 256, 256, 0, stream>>>(row, cnt);
    k_scan1<<<SCAN_BLOCKS, 256, 0, stream>>>(cnt, row_ptr, bsum);
    k_scan2<<<1, 512, 0, stream>>>(bsum, bbase);
    k_scan3<<<SCAN_BLOCKS, 256, 0, stream>>>(row_ptr, bbase, woff);
    k_scatter<<<(NE + 255) / 256, 256, 0, stream>>>(row, col, woff, cols);

    k_enc1<<<NN / 32, 256, 0, stream>>>(x, enc_w1, enc_b1, h);
    k_enc2<<<NT, 256, 0, stream>>>(h, enc_w2, enc_b2, feats);

    for (int i = 0; i < NL; i++) {
        k_ab<<<NT, 256, 0, stream>>>(feats, conv_w + (size_t)i * 2 * H * H,
                                     conv_b + (size_t)i * H, Abuf, Bbuf);
        k_gather<<<NN / 4, 256, 0, stream>>>(Abuf, Bbuf, row_ptr, cols,
                                             bn_gamma + (size_t)i * H,
                                             bn_beta + (size_t)i * H, feats);
    }

    k_head<<<NT, 256, 0, stream>>>(feats, out_w1, out_b1, out_w2, out_b2,
                                   out_w3, out_b3, out);
    k_batch<<<(NN + 255) / 256, 256, 0, stream>>>(batch, out + (size_t)NN * CDIM);
}

// Round 6
// 580.088 us; speedup vs baseline: 5.2640x; 1.0621x over previous
//
#include <hip/hip_runtime.h>

#define NN 100000
#define NE 800000
#define FIN 16
#define H 64
#define NL 4
#define CDIM 8
#define SCAN_BLOCKS ((NN + 255) / 256)  // 391
#define NT 1563                          // ceil(NN/64)

// fast ELU: __expf -> native v_exp_f32; abs err of (exp(x)-1) vs expm1 <= ~1 ulp(1.0) ~ 1.2e-7
__device__ __forceinline__ float elu(float x) { return x > 0.f ? x : __expf(x) - 1.f; }
__device__ __forceinline__ float4 elu4(float4 v) {
    return make_float4(elu(v.x), elu(v.y), elu(v.z), elu(v.w));
}

// ---------------- CSR build ----------------
__global__ __launch_bounds__(256) void k_zero_cnt(int* cnt) {
    int i = blockIdx.x * 256 + threadIdx.x;
    if (i < NN) cnt[i] = 0;
}

__global__ __launch_bounds__(256) void k_count(const int* __restrict__ row, int* cnt) {
    int e = blockIdx.x * 256 + threadIdx.x;
    if (e < NE) atomicAdd(&cnt[row[e]], 1);
}

__global__ __launch_bounds__(256) void k_scan1(const int* __restrict__ cnt,
                                               int* __restrict__ row_ptr,
                                               int* __restrict__ bsum) {
    __shared__ int s[256];
    int t = threadIdx.x, i = blockIdx.x * 256 + t;
    int v = (i < NN) ? cnt[i] : 0;
    s[t] = v;
    __syncthreads();
    for (int off = 1; off < 256; off <<= 1) {
        int x = (t >= off) ? s[t - off] : 0;
        __syncthreads();
        s[t] += x;
        __syncthreads();
    }
    if (i < NN) row_ptr[i] = s[t] - v;
    if (t == 255) bsum[blockIdx.x] = s[255];
}

__global__ __launch_bounds__(512) void k_scan2(const int* __restrict__ bsum,
                                               int* __restrict__ bbase) {
    __shared__ int s[512];
    int t = threadIdx.x;
    int v = (t < SCAN_BLOCKS) ? bsum[t] : 0;
    s[t] = v;
    __syncthreads();
    for (int off = 1; off < 512; off <<= 1) {
        int x = (t >= off) ? s[t - off] : 0;
        __syncthreads();
        s[t] += x;
        __syncthreads();
    }
    if (t < SCAN_BLOCKS) bbase[t] = s[t] - v;
}

__global__ __launch_bounds__(256) void k_scan3(int* __restrict__ row_ptr,
                                               const int* __restrict__ bbase,
                                               int* __restrict__ woff) {
    int t = threadIdx.x, i = blockIdx.x * 256 + t;
    if (i < NN) {
        int v = row_ptr[i] + bbase[blockIdx.x];
        row_ptr[i] = v;
        woff[i] = v;
    }
    if (i == 0) row_ptr[NN] = NE;
}

__global__ __launch_bounds__(256) void k_scatter(const int* __restrict__ row,
                                                 const int* __restrict__ col,
                                                 int* woff, int* __restrict__ cols) {
    int e = blockIdx.x * 256 + threadIdx.x;
    if (e < NE) {
        int r = row[e];
        int p = atomicAdd(&woff[r], 1);
        cols[p] = col[e];
    }
}

// ---------------- encoder L1: h = ELU(x @ w1 + b1), x:(N,16) ----------------
__global__ __launch_bounds__(256) void k_enc1(const float* __restrict__ x,
                                              const float* __restrict__ w1,
                                              const float* __restrict__ b1,
                                              float* __restrict__ h) {
    __shared__ float w1s[FIN * H];
    int tid = threadIdx.x;
    int q = tid >> 6, j = tid & 63;
    for (int t = tid; t < FIN * H; t += 256) w1s[t] = w1[t];
    __syncthreads();
    float bb = b1[j];
    int base = blockIdx.x * 32;
    for (int i = 0; i < 8; i++) {
        int n = base + i * 4 + q;
        float acc = bb;
#pragma unroll
        for (int k = 0; k < FIN; k++) acc += x[n * FIN + k] * w1s[k * H + j];
        h[n * H + j] = elu(acc);
    }
}

// ---------------- encoder L2: feats = ELU(h @ w2 + b2), M4xC4 tile ----------------
__global__ __launch_bounds__(256) void k_enc2(const float* __restrict__ h,
                                              const float* __restrict__ w2,
                                              const float* __restrict__ b2,
                                              float* __restrict__ feats) {
    __shared__ __align__(16) float fs[64 * 68];
    __shared__ __align__(16) float ws[64 * 64];
    int tid = threadIdx.x;
    int base = blockIdx.x * 64;
#pragma unroll
    for (int r = 0; r < 4; r++) {
        int idx = tid + 256 * r;
        ((float4*)ws)[idx] = ((const float4*)w2)[idx];
        int rw = idx >> 4, cc = idx & 15;
        int n = base + rw; if (n >= NN) n = NN - 1;
        *(float4*)&fs[rw * 68 + cc * 4] = *(const float4*)&h[(size_t)n * 64 + cc * 4];
    }
    __syncthreads();
    int cg = tid & 15, ng = tid >> 4;
    int c0 = cg * 4;
    float4 bb = ((const float4*)b2)[cg];
    float4 acc[4];
    acc[0] = bb; acc[1] = bb; acc[2] = bb; acc[3] = bb;
#pragma unroll 2
    for (int kq = 0; kq < 16; kq++) {
        int k0 = kq * 4;
        float4 w0 = *(const float4*)&ws[(k0 + 0) * 64 + c0];
        float4 w1v = *(const float4*)&ws[(k0 + 1) * 64 + c0];
        float4 w2v = *(const float4*)&ws[(k0 + 2) * 64 + c0];
        float4 w3v = *(const float4*)&ws[(k0 + 3) * 64 + c0];
#pragma unroll
        for (int m = 0; m < 4; m++) {
            float4 f = *(const float4*)&fs[(ng * 4 + m) * 68 + k0];
            acc[m].x += f.x * w0.x + f.y * w1v.x + f.z * w2v.x + f.w * w3v.x;
            acc[m].y += f.x * w0.y + f.y * w1v.y + f.z * w2v.y + f.w * w3v.y;
            acc[m].z += f.x * w0.z + f.y * w1v.z + f.z * w2v.z + f.w * w3v.z;
            acc[m].w += f.x * w0.w + f.y * w1v.w + f.z * w2v.w + f.w * w3v.w;
        }
    }
#pragma unroll
    for (int m = 0; m < 4; m++) {
        int n = base + ng * 4 + m;
        if (n < NN) *(float4*)&feats[(size_t)n * 64 + c0] = elu4(acc[m]);
    }
}

// ---- A = f@(Wt-Wb)+cb ; B = f@Wb ; M4xC4, TWO k-passes (register pressure) ----
__global__ __launch_bounds__(256) void k_ab(const float* __restrict__ feats,
                                            const float* __restrict__ convw,
                                            const float* __restrict__ convb,
                                            float* __restrict__ A, float* __restrict__ Bm) {
    __shared__ __align__(16) float fs[64 * 68];
    __shared__ __align__(16) float was[64 * 64];
    __shared__ __align__(16) float wbs[64 * 64];
    int tid = threadIdx.x;
    int base = blockIdx.x * 64;
#pragma unroll
    for (int r = 0; r < 4; r++) {
        int idx = tid + 256 * r;
        float4 wt = ((const float4*)convw)[idx];
        float4 wb = ((const float4*)convw)[1024 + idx];
        ((float4*)was)[idx] = make_float4(wt.x - wb.x, wt.y - wb.y, wt.z - wb.z, wt.w - wb.w);
        ((float4*)wbs)[idx] = wb;
        int rw = idx >> 4, cc = idx & 15;
        int n = base + rw; if (n >= NN) n = NN - 1;
        *(float4*)&fs[rw * 68 + cc * 4] = *(const float4*)&feats[(size_t)n * 64 + cc * 4];
    }
    __syncthreads();
    int cg = tid & 15, ng = tid >> 4;
    int c0 = cg * 4;

    // pass 1: A = f @ (Wt-Wb) + cb
    {
        float4 cb = ((const float4*)convb)[cg];
        float4 acc[4];
        acc[0] = cb; acc[1] = cb; acc[2] = cb; acc[3] = cb;
#pragma unroll 2
        for (int kq = 0; kq < 16; kq++) {
            int k0 = kq * 4;
            float4 w0 = *(const float4*)&was[(k0 + 0) * 64 + c0];
            float4 w1v = *(const float4*)&was[(k0 + 1) * 64 + c0];
            float4 w2v = *(const float4*)&was[(k0 + 2) * 64 + c0];
            float4 w3v = *(const float4*)&was[(k0 + 3) * 64 + c0];
#pragma unroll
            for (int m = 0; m < 4; m++) {
                float4 f = *(const float4*)&fs[(ng * 4 + m) * 68 + k0];
                acc[m].x += f.x * w0.x + f.y * w1v.x + f.z * w2v.x + f.w * w3v.x;
                acc[m].y += f.x * w0.y + f.y * w1v.y + f.z * w2v.y + f.w * w3v.y;
                acc[m].z += f.x * w0.z + f.y * w1v.z + f.z * w2v.z + f.w * w3v.z;
                acc[m].w += f.x * w0.w + f.y * w1v.w + f.z * w2v.w + f.w * w3v.w;
            }
        }
#pragma unroll
        for (int m = 0; m < 4; m++) {
            int n = base + ng * 4 + m;
            if (n < NN) *(float4*)&A[(size_t)n * 64 + c0] = acc[m];
        }
    }

    // pass 2: B = f @ Wb
    {
        float4 z = make_float4(0.f, 0.f, 0.f, 0.f);
        float4 acc[4];
        acc[0] = z; acc[1] = z; acc[2] = z; acc[3] = z;
#pragma unroll 2
        for (int kq = 0; kq < 16; kq++) {
            int k0 = kq * 4;
            float4 w0 = *(const float4*)&wbs[(k0 + 0) * 64 + c0];
            float4 w1v = *(const float4*)&wbs[(k0 + 1) * 64 + c0];
            float4 w2v = *(const float4*)&wbs[(k0 + 2) * 64 + c0];
            float4 w3v = *(const float4*)&wbs[(k0 + 3) * 64 + c0];
#pragma unroll
            for (int m = 0; m < 4; m++) {
                float4 f = *(const float4*)&fs[(ng * 4 + m) * 68 + k0];
                acc[m].x += f.x * w0.x + f.y * w1v.x + f.z * w2v.x + f.w * w3v.x;
                acc[m].y += f.x * w0.y + f.y * w1v.y + f.z * w2v.y + f.w * w3v.y;
                acc[m].z += f.x * w0.z + f.y * w1v.z + f.z * w2v.z + f.w * w3v.z;
                acc[m].w += f.x * w0.w + f.y * w1v.w + f.z * w2v.w + f.w * w3v.w;
            }
        }
#pragma unroll
        for (int m = 0; m < 4; m++) {
            int n = base + ng * 4 + m;
            if (n < NN) *(float4*)&Bm[(size_t)n * 64 + c0] = acc[m];
        }
    }
}

// ---------------- CSR gather: 4 edges per instr, no atomics ----------------
__global__ __launch_bounds__(256) void k_gather(const float* __restrict__ A,
                                                const float* __restrict__ Bm,
                                                const int* __restrict__ row_ptr,
                                                const int* __restrict__ cols,
                                                const float* __restrict__ gamma,
                                                const float* __restrict__ beta,
                                                float* __restrict__ feats) {
    int tid = threadIdx.x;
    int wave = tid >> 6, lane = tid & 63;
    int n = blockIdx.x * 4 + wave;
    int g = lane >> 4, c4 = lane & 15, c0 = c4 * 4;
    int s = row_ptr[n], e = row_ptr[n + 1];
    int cnt = e - s;
    float4 a = *(const float4*)&A[(size_t)n * H + c0];
    float4 acc = make_float4(0.f, 0.f, 0.f, 0.f);
    for (int p0 = s; p0 < e; p0 += 4) {
        int p = p0 + g;
        bool valid = p < e;
        int c = cols[valid ? p : (e - 1)];
        float4 b = *(const float4*)&Bm[(size_t)c * H + c0];
        float4 v = elu4(make_float4(a.x + b.x, a.y + b.y, a.z + b.z, a.w + b.w));
        if (valid) {
            acc.x += v.x; acc.y += v.y; acc.z += v.z; acc.w += v.w;
        }
    }
    acc.x += __shfl_xor(acc.x, 16); acc.y += __shfl_xor(acc.y, 16);
    acc.z += __shfl_xor(acc.z, 16); acc.w += __shfl_xor(acc.w, 16);
    acc.x += __shfl_xor(acc.x, 32); acc.y += __shfl_xor(acc.y, 32);
    acc.z += __shfl_xor(acc.z, 32); acc.w += __shfl_xor(acc.w, 32);
    if (g == 0 && cnt > 0) {
        const float bs = 0.99999500003749968750f;  // 1/sqrt(1+1e-5)
        float inv = bs / (float)cnt;
        float4 gm = *(const float4*)&gamma[c0];
        float4 bt = *(const float4*)&beta[c0];
        float4 f = *(float4*)&feats[(size_t)n * H + c0];
        f.x += acc.x * gm.x * inv + bt.x;
        f.y += acc.y * gm.y * inv + bt.y;
        f.z += acc.z * gm.z * inv + bt.z;
        f.w += acc.w * gm.w * inv + bt.w;
        *(float4*)&feats[(size_t)n * H + c0] = f;
    }
}

// ---------------- fused 3-layer head (+ batch passthrough) ----------------
__global__ __launch_bounds__(256) void k_head(const float* __restrict__ feats,
                                              const float* __restrict__ w1,
                                              const float* __restrict__ b1,
                                              const float* __restrict__ w2,
                                              const float* __restrict__ b2,
                                              const float* __restrict__ w3,
                                              const float* __restrict__ b3,
                                              const int* __restrict__ batch,
                                              float* __restrict__ out,
                                              float* __restrict__ out2) {
    __shared__ __align__(16) float fs[64 * 68];   // also reused as o2s
    __shared__ __align__(16) float w1s[64 * 64];
    __shared__ __align__(16) float o1s[64 * 68];
    __shared__ __align__(16) float w2s[64 * 32];
    __shared__ __align__(16) float w3s[32 * 8];
    int tid = threadIdx.x;
    int base = blockIdx.x * 64;
#pragma unroll
    for (int r = 0; r < 4; r++) {
        int idx = tid + 256 * r;
        ((float4*)w1s)[idx] = ((const float4*)w1)[idx];
        int rw = idx >> 4, cc = idx & 15;
        int n = base + rw; if (n >= NN) n = NN - 1;
        *(float4*)&fs[rw * 68 + cc * 4] = *(const float4*)&feats[(size_t)n * 64 + cc * 4];
    }
    ((float4*)w2s)[tid] = ((const float4*)w2)[tid];
    ((float4*)w2s)[tid + 256] = ((const float4*)w2)[tid + 256];
    if (tid < 64) ((float4*)w3s)[tid] = ((const float4*)w3)[tid];
    // fused batch passthrough
    if (tid < 64) {
        int n = base + tid;
        if (n < NN) out2[n] = (float)batch[n];
    }
    __syncthreads();

    // layer 1: 64->64, M4xC4
    int cg = tid & 15, ng = tid >> 4;
    int c0 = cg * 4;
    {
        float4 bb = ((const float4*)b1)[cg];
        float4 acc[4];
        acc[0] = bb; acc[1] = bb; acc[2] = bb; acc[3] = bb;
#pragma unroll 2
        for (int kq = 0; kq < 16; kq++) {
            int k0 = kq * 4;
            float4 w0 = *(const float4*)&w1s[(k0 + 0) * 64 + c0];
            float4 w1v = *(const float4*)&w1s[(k0 + 1) * 64 + c0];
            float4 w2v = *(const float4*)&w1s[(k0 + 2) * 64 + c0];
            float4 w3v = *(const float4*)&w1s[(k0 + 3) * 64 + c0];
#pragma unroll
            for (int m = 0; m < 4; m++) {
                float4 f = *(const float4*)&fs[(ng * 4 + m) * 68 + k0];
                acc[m].x += f.x * w0.x + f.y * w1v.x + f.z * w2v.x + f.w * w3v.x;
                acc[m].y += f.x * w0.y + f.y * w1v.y + f.z * w2v.y + f.w * w3v.y;
                acc[m].z += f.x * w0.z + f.y * w1v.z + f.z * w2v.z + f.w * w3v.z;
                acc[m].w += f.x * w0.w + f.y * w1v.w + f.z * w2v.w + f.w * w3v.w;
            }
        }
        __syncthreads();  // all fs reads done (fs reused below)
#pragma unroll
        for (int m = 0; m < 4; m++)
            *(float4*)&o1s[(ng * 4 + m) * 68 + c0] = elu4(acc[m]);
    }
    __syncthreads();

    // layer 2: 64->32, M2xC4
    float* o2s = fs;  // alias; fs is dead
    {
        int cg2 = tid & 7, ng2 = tid >> 3;
        int c20 = cg2 * 4;
        float4 bb = ((const float4*)b2)[cg2];
        float4 acc[2];
        acc[0] = bb; acc[1] = bb;
#pragma unroll 2
        for (int kq = 0; kq < 16; kq++) {
            int k0 = kq * 4;
            float4 w0 = *(const float4*)&w2s[(k0 + 0) * 32 + c20];
            float4 w1v = *(const float4*)&w2s[(k0 + 1) * 32 + c20];
            float4 w2v = *(const float4*)&w2s[(k0 + 2) * 32 + c20];
            float4 w3v = *(const float4*)&w2s[(k0 + 3) * 32 + c20];
#pragma unroll
            for (int m = 0; m < 2; m++) {
                float4 f = *(const float4*)&o1s[(ng2 * 2 + m) * 68 + k0];
                acc[m].x += f.x * w0.x + f.y * w1v.x + f.z * w2v.x + f.w * w3v.x;
                acc[m].y += f.x * w0.y + f.y * w1v.y + f.z * w2v.y + f.w * w3v.y;
                acc[m].z += f.x * w0.z + f.y * w1v.z + f.z * w2v.z + f.w * w3v.z;
                acc[m].w += f.x * w0.w + f.y * w1v.w + f.z * w2v.w + f.w * w3v.w;
            }
        }
#pragma unroll
        for (int m = 0; m < 2; m++)
            *(float4*)&o2s[(ng2 * 2 + m) * 40 + c20] = elu4(acc[m]);
    }
    __syncthreads();

    // layer 3: 32->8, first 128 threads, M1xC4
    if (tid < 128) {
        int n3 = tid >> 1, c30 = (tid & 1) * 4;
        float4 acc = ((const float4*)b3)[tid & 1];
#pragma unroll 2
        for (int kq = 0; kq < 8; kq++) {
            int k0 = kq * 4;
            float4 w0 = *(const float4*)&w3s[(k0 + 0) * 8 + c30];
            float4 w1v = *(const float4*)&w3s[(k0 + 1) * 8 + c30];
            float4 w2v = *(const float4*)&w3s[(k0 + 2) * 8 + c30];
            float4 w3v = *(const float4*)&w3s[(k0 + 3) * 8 + c30];
            float4 f = *(const float4*)&o2s[n3 * 40 + k0];
            acc.x += f.x * w0.x + f.y * w1v.x + f.z * w2v.x + f.w * w3v.x;
            acc.y += f.x * w0.y + f.y * w1v.y + f.z * w2v.y + f.w * w3v.y;
            acc.z += f.x * w0.z + f.y * w1v.z + f.z * w2v.z + f.w * w3v.z;
            acc.w += f.x * w0.w + f.y * w1v.w + f.z * w2v.w + f.w * w3v.w;
        }
        int n = base + n3;
        if (n < NN) *(float4*)&out[(size_t)n * 8 + c30] = acc;
    }
}

extern "C" void kernel_launch(void* const* d_in, const int* in_sizes, int n_in,
                              void* d_out, int out_size, void* d_ws, size_t ws_size,
                              hipStream_t stream) {
    const float* x = (const float*)d_in[0];
    const int* edge_index = (const int*)d_in[1];
    const int* batch = (const int*)d_in[2];
    const float* enc_w1 = (const float*)d_in[3];
    const float* enc_b1 = (const float*)d_in[4];
    const float* enc_w2 = (const float*)d_in[5];
    const float* enc_b2 = (const float*)d_in[6];
    const float* conv_w = (const float*)d_in[7];
    const float* conv_b = (const float*)d_in[8];
    const float* bn_gamma = (const float*)d_in[9];
    const float* bn_beta = (const float*)d_in[10];
    const float* out_w1 = (const float*)d_in[11];
    const float* out_b1 = (const float*)d_in[12];
    const float* out_w2 = (const float*)d_in[13];
    const float* out_b2 = (const float*)d_in[14];
    const float* out_w3 = (const float*)d_in[15];
    const float* out_b3 = (const float*)d_in[16];

    const int* row = edge_index;
    const int* col = edge_index + NE;

    float* feats = (float*)d_ws;               // N*H
    float* Abuf = feats + (size_t)NN * H;      // N*H
    float* Bbuf = Abuf + (size_t)NN * H;       // N*H
    int* cnt = (int*)(Bbuf + (size_t)NN * H);  // N
    int* row_ptr = cnt + NN;                   // N+1
    int* woff = row_ptr + NN + 1;              // N
    int* cols = woff + NN;                     // E
    int* bsum = cols + NE;                     // 512
    int* bbase = bsum + 512;                   // 512
    float* h = Abuf;                           // encoder hidden reuses A

    float* out = (float*)d_out;

    k_zero_cnt<<<(NN + 255) / 256, 256, 0, stream>>>(cnt);
    k_count<<<(NE + 255) / 256, 256, 0, stream>>>(row, cnt);
    k_scan1<<<SCAN_BLOCKS, 256, 0, stream>>>(cnt, row_ptr, bsum);
    k_scan2<<<1, 512, 0, stream>>>(bsum, bbase);
    k_scan3<<<SCAN_BLOCKS, 256, 0, stream>>>(row_ptr, bbase, woff);
    k_scatter<<<(NE + 255) / 256, 256, 0, stream>>>(row, col, woff, cols);

    k_enc1<<<NN / 32, 256, 0, stream>>>(x, enc_w1, enc_b1, h);
    k_enc2<<<NT, 256, 0, stream>>>(h, enc_w2, enc_b2, feats);

    for (int i = 0; i < NL; i++) {
        k_ab<<<NT, 256, 0, stream>>>(feats, conv_w + (size_t)i * 2 * H * H,
                                     conv_b + (size_t)i * H, Abuf, Bbuf);
        k_gather<<<NN / 4, 256, 0, stream>>>(Abuf, Bbuf, row_ptr, cols,
                                             bn_gamma + (size_t)i * H,
                                             bn_beta + (size_t)i * H, feats);
    }

    k_head<<<NT, 256, 0, stream>>>(feats, out_w1, out_b1, out_w2, out_b2,
                                   out_w3, out_b3, batch, out,
                                   out + (size_t)NN * CDIM);
}